// Round 8
// baseline (411.083 us; speedup 1.0000x reference)
//
#include <hip/hip_runtime.h>

// Problem constants (fixed shapes)
#define BB 8192      // batch
#define DZ 1024
#define DS 64
#define DH 4096
#define KEXT (DH + DS)   // 4160: K of GEMM2 = [H | s]

typedef float floatx4 __attribute__((ext_vector_type(4)));
typedef __bf16 bf16x8 __attribute__((ext_vector_type(8)));
typedef __bf16 bf16x4 __attribute__((ext_vector_type(4)));
typedef __attribute__((address_space(1))) void* as1_void_ptr;
typedef __attribute__((address_space(3))) void* as3_void_ptr;

// s_waitcnt immediates (gfx9: vmcnt[3:0] bits0-3 + [5:4] bits15:14,
// expcnt bits6:4, lgkmcnt bits11:8). lgkm=15,exp=7 unconstrained base = 3952.
#define WAIT_VM0   3952   // vmcnt(0)
#define WAIT_VM4   3956   // vmcnt(4)
#define WAIT_LGKM0 49279  // lgkmcnt(0), vm/exp unconstrained

__device__ __forceinline__ void async_copy16(const void* g, void* l) {
    // global -> LDS direct copy, 16B/lane; per-lane GLOBAL address,
    // wave-uniform LDS base + lane*16 dest.
    __builtin_amdgcn_global_load_lds((as1_void_ptr)g, (as3_void_ptr)l, 16, 0, 0);
}

__device__ __forceinline__ bf16x4 cvt4(float4 v) {
    bf16x4 o = { (__bf16)v.x, (__bf16)v.y, (__bf16)v.z, (__bf16)v.w };
    return o;
}

// ---------------- merged prep kernel (all stores 8B) ----------------
__global__ void prep_all(const float* __restrict__ z, const float* __restrict__ W1,
                         const float* __restrict__ W2, const float* __restrict__ C,
                         const float* __restrict__ s,
                         __bf16* __restrict__ zb, __bf16* __restrict__ W1b,
                         __bf16* __restrict__ B2b, __bf16* __restrict__ Hb) {
    const int b = blockIdx.x, t = threadIdx.x;
    if (b < 8192) {
        int i = b * 256 + t;
        *(bf16x4*)(zb + (size_t)i * 4) = cvt4(((const float4*)z)[i]);
    } else if (b < 12288) {
        int i = (b - 8192) * 256 + t;
        *(bf16x4*)(W1b + (size_t)i * 4) = cvt4(((const float4*)W1)[i]);
    } else if (b < 13312) {
        int j = b - 12288;
        const float* wrow = W2 + (size_t)j * DH;
        const float* crow = C + (size_t)j * DS;
        __bf16* orow = B2b + (size_t)j * KEXT;
        for (int c = t; c < 520; c += 256) {   // 520 chunks of 8 elems
            int h = c * 8;
            const float* src = (h < DH) ? (wrow + h) : (crow + (h - DH));
            *(bf16x4*)(orow + h)     = cvt4(*(const float4*)(src));
            *(bf16x4*)(orow + h + 4) = cvt4(*(const float4*)(src + 4));
        }
    } else {
        int i = (b - 13312) * 256 + t;        // 0 .. 131071 chunks of 4
        int r = i >> 4, k = (i & 15) * 4;
        float4 v = *(const float4*)(s + (size_t)r * DS + k);
        *(bf16x4*)(Hb + (size_t)r * KEXT + DH + k) = cvt4(v);
    }
}

// ---------------- GEMM structure (both kernels) ----------------
// 128x128 tile, 4 waves, wave (wm,wn) owns 64x64 via 4x4 grid of 16x16x32
// bf16 MFMA (m97 fragment layout; 2-way LDS aliasing = free).
//  - A operand: global_load_lds staging, BK=64 (2 panels of 128x32, 64B row
//    stride), double-buffered (32 KB), raw s_barrier + manual vmcnt.
//  - B operand: LDS BYPASS. Fragments loaded global->VGPR directly
//    (dwordx4/lane; 16 aligned 64B lines per frag-load, L1/L2-hot weight
//    panel). Halves LDS port traffic - the measured bottleneck (r7:
//    128 ds_read_b128 + 48 KB writes/iter ~ 1900 cyc of 3360 cyc/iter).
//  - Issue order per iter: [B(kt) x8 plain loads, A(kt+1) x4 copies], then
//    vmcnt(4): FIFO drains A(kt)+B(kt), keeps A(kt+1) in flight.

// ---------------- GEMM1: Hb[:, :4096] = relu(zb @ W1b^T + h1) ----------------
// A = zb [8192 x 1024] K-major, B = W1b [4096 x 1024] K-major. KITER=16.
__global__ __launch_bounds__(256) void gemm1_relu(
    const __bf16* __restrict__ Ag, const __bf16* __restrict__ Bg,
    const float* __restrict__ h1, __bf16* __restrict__ Hb)
{
    constexpr int ldA = DZ, ldB = DZ, KITER = DZ / 64;
    __shared__ __align__(16) __bf16 As[2 * 128 * 64];   // [buf][panel][128][32] = 32 KB

    const int tid = threadIdx.x;
    const int wave = tid >> 6, lane = tid & 63;
    const int wm = wave >> 1, wn = wave & 1;
    const int row0 = blockIdx.x * 128;
    const int col0 = blockIdx.y * 128;

    const __bf16* pA = Ag + (size_t)(row0 + (tid >> 2)) * ldA + (tid & 3) * 8;
    // per-lane B fragment base: row = col0 + wn*64 + (lane&15), k-chunk = lane>>4
    const __bf16* pBf = Bg + (size_t)(col0 + wn * 64 + (lane & 15)) * ldB + (lane >> 4) * 8;
    const __bf16* Afrag = As + (wm * 64 + (lane & 15)) * 32 + (lane >> 4) * 8;

    floatx4 acc[4][4];
#pragma unroll
    for (int i = 0; i < 4; ++i)
#pragma unroll
        for (int j = 0; j < 4; ++j) acc[i][j] = (floatx4)0.0f;

    {   // prologue: A tile 0 -> buffer 0
        __bf16* lA = As + wave * 512;
        async_copy16(pA,                          lA);
        async_copy16(pA + (size_t)64 * ldA,       lA + 2048);
        async_copy16(pA + 32,                     lA + 4096);
        async_copy16(pA + (size_t)64 * ldA + 32,  lA + 4096 + 2048);
    }

    for (int kt = 0; kt < KITER; ++kt) {
        const int p = kt & 1;

        // B fragments for this K-tile: direct global->VGPR
        bf16x8 bfr[2][4];
#pragma unroll
        for (int ks = 0; ks < 2; ++ks)
#pragma unroll
            for (int j = 0; j < 4; ++j)
                bfr[ks][j] = *(const bf16x8*)(pBf + (size_t)j * 16 * ldB + kt * 64 + ks * 32);

        if (kt + 1 < KITER) {
            const __bf16* ak = pA + (kt + 1) * 64;
            __bf16* lA = As + (p ^ 1) * 8192 + wave * 512;
            async_copy16(ak,                          lA);
            async_copy16(ak + (size_t)64 * ldA,       lA + 2048);
            async_copy16(ak + 32,                     lA + 4096);
            async_copy16(ak + (size_t)64 * ldA + 32,  lA + 4096 + 2048);
            __builtin_amdgcn_s_waitcnt(WAIT_VM4);   // A(kt)+B(kt) done; A(kt+1) flying
        } else {
            __builtin_amdgcn_s_waitcnt(WAIT_VM0);
        }
        __builtin_amdgcn_s_barrier();

#pragma unroll
        for (int ks = 0; ks < 2; ++ks) {
            bf16x8 af[4];
#pragma unroll
            for (int i = 0; i < 4; ++i)
                af[i] = *(const bf16x8*)(Afrag + p * 8192 + ks * 4096 + i * 16 * 32);
#pragma unroll
            for (int i = 0; i < 4; ++i)
#pragma unroll
                for (int j = 0; j < 4; ++j)
                    acc[i][j] = __builtin_amdgcn_mfma_f32_16x16x32_bf16(af[i], bfr[ks][j], acc[i][j], 0, 0, 0);
        }

        __builtin_amdgcn_s_waitcnt(WAIT_LGKM0);     // reads of buf p done
        __builtin_amdgcn_s_barrier();               // safe to refill buf p
    }

    // epilogue: C/D layout col = lane&15, row = (lane>>4)*4 + reg
    const int r0 = row0 + wm * 64 + (lane >> 4) * 4;
    const int c0 = col0 + wn * 64 + (lane & 15);
#pragma unroll
    for (int i = 0; i < 4; ++i) {
#pragma unroll
        for (int j = 0; j < 4; ++j) {
            int c = c0 + j * 16;
            float bias = h1[c];
#pragma unroll
            for (int rg = 0; rg < 4; ++rg) {
                int r = r0 + i * 16 + rg;
                float v = acc[i][j][rg] + bias;
                v = v > 0.0f ? v : 0.0f;
                Hb[(size_t)r * KEXT + c] = (__bf16)v;
            }
        }
    }
}

// ---------------- GEMM2: out = Hb @ B2b^T + A*zb + h2 ----------------
// A = Hb [8192 x 4160] K-major, B = B2b [1024 x 4160] K-major. KITER=65.
__global__ __launch_bounds__(256) void gemm2_out(
    const __bf16* __restrict__ Ag, const __bf16* __restrict__ Bg,
    const float* __restrict__ Adiag, const float* __restrict__ h2,
    const __bf16* __restrict__ zb, float* __restrict__ out)
{
    constexpr int ldA = KEXT, ldB = KEXT, KITER = KEXT / 64;
    __shared__ __align__(16) __bf16 As[2 * 128 * 64];   // 32 KB

    const int tid = threadIdx.x;
    const int wave = tid >> 6, lane = tid & 63;
    const int wm = wave >> 1, wn = wave & 1;
    const int row0 = blockIdx.x * 128;
    const int col0 = blockIdx.y * 128;

    const __bf16* pA = Ag + (size_t)(row0 + (tid >> 2)) * ldA + (tid & 3) * 8;
    const __bf16* pBf = Bg + (size_t)(col0 + wn * 64 + (lane & 15)) * ldB + (lane >> 4) * 8;
    const __bf16* Afrag = As + (wm * 64 + (lane & 15)) * 32 + (lane >> 4) * 8;

    floatx4 acc[4][4];
#pragma unroll
    for (int i = 0; i < 4; ++i)
#pragma unroll
        for (int j = 0; j < 4; ++j) acc[i][j] = (floatx4)0.0f;

    {   // prologue: A tile 0 -> buffer 0
        __bf16* lA = As + wave * 512;
        async_copy16(pA,                          lA);
        async_copy16(pA + (size_t)64 * ldA,       lA + 2048);
        async_copy16(pA + 32,                     lA + 4096);
        async_copy16(pA + (size_t)64 * ldA + 32,  lA + 4096 + 2048);
    }

    for (int kt = 0; kt < KITER; ++kt) {
        const int p = kt & 1;

        bf16x8 bfr[2][4];
#pragma unroll
        for (int ks = 0; ks < 2; ++ks)
#pragma unroll
            for (int j = 0; j < 4; ++j)
                bfr[ks][j] = *(const bf16x8*)(pBf + (size_t)j * 16 * ldB + kt * 64 + ks * 32);

        if (kt + 1 < KITER) {
            const __bf16* ak = pA + (kt + 1) * 64;
            __bf16* lA = As + (p ^ 1) * 8192 + wave * 512;
            async_copy16(ak,                          lA);
            async_copy16(ak + (size_t)64 * ldA,       lA + 2048);
            async_copy16(ak + 32,                     lA + 4096);
            async_copy16(ak + (size_t)64 * ldA + 32,  lA + 4096 + 2048);
            __builtin_amdgcn_s_waitcnt(WAIT_VM4);
        } else {
            __builtin_amdgcn_s_waitcnt(WAIT_VM0);
        }
        __builtin_amdgcn_s_barrier();

#pragma unroll
        for (int ks = 0; ks < 2; ++ks) {
            bf16x8 af[4];
#pragma unroll
            for (int i = 0; i < 4; ++i)
                af[i] = *(const bf16x8*)(Afrag + p * 8192 + ks * 4096 + i * 16 * 32);
#pragma unroll
            for (int i = 0; i < 4; ++i)
#pragma unroll
                for (int j = 0; j < 4; ++j)
                    acc[i][j] = __builtin_amdgcn_mfma_f32_16x16x32_bf16(af[i], bfr[ks][j], acc[i][j], 0, 0, 0);
        }

        __builtin_amdgcn_s_waitcnt(WAIT_LGKM0);
        __builtin_amdgcn_s_barrier();
    }

    const int r0 = row0 + wm * 64 + (lane >> 4) * 4;
    const int c0 = col0 + wn * 64 + (lane & 15);
#pragma unroll
    for (int i = 0; i < 4; ++i) {
#pragma unroll
        for (int j = 0; j < 4; ++j) {
            const int c = c0 + j * 16;
            const float aj = Adiag[c];
            const float hj = h2[c];
#pragma unroll
            for (int rg = 0; rg < 4; ++rg) {
                const int r = r0 + i * 16 + rg;
                out[(size_t)r * DZ + c] =
                    acc[i][j][rg] + aj * (float)zb[(size_t)r * DZ + c] + hj;
            }
        }
    }
}

// ---------------- launch ----------------

extern "C" void kernel_launch(void* const* d_in, const int* in_sizes, int n_in,
                              void* d_out, int out_size, void* d_ws, size_t ws_size,
                              hipStream_t stream) {
    const float* z  = (const float*)d_in[0];   // [8192,1024]
    const float* s  = (const float*)d_in[1];   // [8192,64]
    const float* A  = (const float*)d_in[2];   // [1024]
    const float* W1 = (const float*)d_in[3];   // [4096,1024]
    const float* W2 = (const float*)d_in[4];   // [1024,4096]
    const float* h1 = (const float*)d_in[5];   // [4096]
    const float* h2 = (const float*)d_in[6];   // [1024]
    const float* C  = (const float*)d_in[7];   // [1024,64]
    float* out = (float*)d_out;

    // workspace layout (bytes): Hb | zb | W1b | B2b  ~= 102 MB total
    char* ws = (char*)d_ws;
    size_t offHb  = 0;
    size_t offZb  = offHb  + (size_t)BB * KEXT * 2;
    size_t offW1b = offZb  + (size_t)BB * DZ * 2;
    size_t offB2b = offW1b + (size_t)DH * DZ * 2;
    __bf16* Hb  = (__bf16*)(ws + offHb);    // [8192 x 4160]
    __bf16* zb  = (__bf16*)(ws + offZb);    // [8192 x 1024]
    __bf16* W1b = (__bf16*)(ws + offW1b);   // [4096 x 1024]
    __bf16* B2b = (__bf16*)(ws + offB2b);   // [1024 x 4160] = [W2 | C]

    prep_all<<<13824, 256, 0, stream>>>(z, W1, W2, C, s, zb, W1b, B2b, Hb);
    gemm1_relu<<<dim3(BB / 128, DH / 128), 256, 0, stream>>>(zb, W1b, h1, Hb);
    gemm2_out<<<dim3(BB / 128, DZ / 128), 256, 0, stream>>>(Hb, B2b, A, h2, zb, out);
}